// Round 1
// baseline (164.131 us; speedup 1.0000x reference)
//
#include <hip/hip_runtime.h>

#define B_DIM 4096
#define L_DIM 2048
#define TPB   256
#define NW    4
#define NBLK  1024               // 4096 rows / 4 waves per block
#define TAU_INV 1.0526315789473684f
#define LOG_TAU_INV 0.05129329438755058f   // ln(1/0.95)

typedef float v4f __attribute__((ext_vector_type(4)));

// Nontemporal float4 load ('nt'): bypasses cache allocation — avoids the L3
// dirty-line service path left by the harness's input restore (prev R6: −13.5us).
__device__ __forceinline__ v4f ntload(const float* p) {
    return __builtin_nontemporal_load((const v4f*)p);
}

__device__ __forceinline__ unsigned nib(v4f y) {
    return (y.x > 0.5f ? 1u : 0u) | (y.y > 0.5f ? 2u : 0u)
         | (y.z > 0.5f ? 4u : 0u) | (y.w > 0.5f ? 8u : 0u);
}

// R8 restructure: ONE WAVE PER ROW — zero barriers / zero cross-wave LDS in
// the hot path. Lane l owns elements {gp*256 + 4l + j} (first half, gp=0..3)
// and {1024 + gp*256 + 4l + j} (second half), all loads 64-lane coalesced 1KB.
// Label cumsum = 4 independent packed wave scans (lo16 = first-half group,
// hi16 = second-half group; counts <= 256 so 16-bit fields are exact).
// Keeps R7's transcendental diet: one log of the 6-factor BCE product per
// element-pair (clamp at -100 provably inactive: p in (1e-4,1-1e-4)), and
// log(1/tau) folded out of the weighted trunc sum.
__global__ __launch_bounds__(TPB) void milecut_row_kernel(
    const float* __restrict__ trunc,
    const float* __restrict__ view1,
    const float* __restrict__ view2,
    const float* __restrict__ view3,
    const float* __restrict__ labels,
    float* __restrict__ partials)
{
    const int t    = threadIdx.x;
    const int lane = t & 63;
    const int wv   = t >> 6;
    const int row  = blockIdx.x * NW + wv;

    __shared__ float srow[NW];
    __shared__ float sbce[NW];

    const size_t base = (size_t)row * L_DIM + 4 * lane;
    const float* Lp = labels + base;
    const float* Tp = trunc  + base;
    const float* P1 = view1  + base;
    const float* P2 = view2  + base;
    const float* P3 = view3  + base;

    // ---- 8 label loads (whole row) ----
    v4f yA0 = ntload(Lp);        v4f yA1 = ntload(Lp + 256);
    v4f yA2 = ntload(Lp + 512);  v4f yA3 = ntload(Lp + 768);
    v4f yB0 = ntload(Lp + 1024); v4f yB1 = ntload(Lp + 1280);
    v4f yB2 = ntload(Lp + 1536); v4f yB3 = ntload(Lp + 1792);

    // ---- pair 0 loads, in flight while the scan runs ----
    v4f tA  = ntload(Tp);        v4f tB  = ntload(Tp + 1024);
    v4f a1  = ntload(P1);        v4f b1  = ntload(P1 + 1024);
    v4f a2  = ntload(P2);        v4f b2  = ntload(P2 + 1024);
    v4f a3  = ntload(P3);        v4f b3  = ntload(P3 + 1024);

    // ---- masks (frees the label regs) ----
    unsigned mA0 = nib(yA0), mA1 = nib(yA1), mA2 = nib(yA2), mA3 = nib(yA3);
    unsigned mB0 = nib(yB0), mB1 = nib(yB1), mB2 = nib(yB2), mB3 = nib(yB3);

    unsigned pv0 = (unsigned)__popc(mA0) | ((unsigned)__popc(mB0) << 16);
    unsigned pv1 = (unsigned)__popc(mA1) | ((unsigned)__popc(mB1) << 16);
    unsigned pv2 = (unsigned)__popc(mA2) | ((unsigned)__popc(mB2) << 16);
    unsigned pv3 = (unsigned)__popc(mA3) | ((unsigned)__popc(mB3) << 16);

    // ---- 4 packed inclusive wave scans (wave-local, barrier-free) ----
    unsigned i0 = pv0, i1 = pv1, i2 = pv2, i3 = pv3;
    #pragma unroll
    for (int o = 1; o < 64; o <<= 1) {
        unsigned n0 = (unsigned)__shfl_up((int)i0, o, 64);
        unsigned n1 = (unsigned)__shfl_up((int)i1, o, 64);
        unsigned n2 = (unsigned)__shfl_up((int)i2, o, 64);
        unsigned n3 = (unsigned)__shfl_up((int)i3, o, 64);
        if (lane >= o) { i0 += n0; i1 += n1; i2 += n2; i3 += n3; }
    }
    unsigned tp0 = (unsigned)__shfl((int)i0, 63, 64);
    unsigned tp1 = (unsigned)__shfl((int)i1, 63, 64);
    unsigned tp2 = (unsigned)__shfl((int)i2, 63, 64);
    unsigned tp3 = (unsigned)__shfl((int)i3, 63, 64);

    unsigned e0 = i0 - pv0, e1 = i1 - pv1, e2 = i2 - pv2, e3 = i3 - pv3; // excl, packed
    unsigned gA0 = tp0 & 0xffffu, gA1 = tp1 & 0xffffu, gA2 = tp2 & 0xffffu, gA3 = tp3 & 0xffffu;
    unsigned gB0 = tp0 >> 16,     gB1 = tp1 >> 16,     gB2 = tp2 >> 16,     gB3 = tp3 >> 16;
    unsigned hA = gA0 + gA1 + gA2 + gA3;
    float ftotal = (float)(hA + gB0 + gB1 + gB2 + gB3);

    // per-pair cumulative bases (+ this lane's exclusive within-group prefix)
    unsigned cbA0 =                    (e0 & 0xffffu);
    unsigned cbA1 = gA0 +              (e1 & 0xffffu);
    unsigned cbA2 = gA0 + gA1 +        (e2 & 0xffffu);
    unsigned cbA3 = gA0 + gA1 + gA2 +  (e3 & 0xffffu);
    unsigned cbB0 = hA +                     (e0 >> 16);
    unsigned cbB1 = hA + gB0 +               (e1 >> 16);
    unsigned cbB2 = hA + gB0 + gB1 +         (e2 >> 16);
    unsigned cbB3 = hA + gB0 + gB1 + gB2 +   (e3 >> 16);

    float esum = 0.f, wtr = 0.f, bce = 0.f;
    const float two_tauinv = 2.0f * TAU_INV;

#define COMPUTE(MAn, MBn, CBA, CBB, IDXBASE, TA, TB, W1A, W1B, W2A, W2B, W3A, W3B) \
    do {                                                                       \
        float tva[4] = {(TA).x, (TA).y, (TA).z, (TA).w};                       \
        float tvb[4] = {(TB).x, (TB).y, (TB).z, (TB).w};                       \
        float w1a[4] = {(W1A).x, (W1A).y, (W1A).z, (W1A).w};                   \
        float w1b[4] = {(W1B).x, (W1B).y, (W1B).z, (W1B).w};                   \
        float w2a[4] = {(W2A).x, (W2A).y, (W2A).z, (W2A).w};                   \
        float w2b[4] = {(W2B).x, (W2B).y, (W2B).z, (W2B).w};                   \
        float w3a[4] = {(W3A).x, (W3A).y, (W3A).z, (W3A).w};                   \
        float w3b[4] = {(W3B).x, (W3B).y, (W3B).z, (W3B).w};                   \
        _Pragma("unroll")                                                      \
        for (int j = 0; j < 4; ++j) {                                          \
            unsigned c1 = (CBA) + (unsigned)__popc((MAn) & ((2u << j) - 1u));  \
            unsigned c2 = (CBB) + (unsigned)__popc((MBn) & ((2u << j) - 1u));  \
            float d1 = (float)((IDXBASE) + j + 1) + ftotal;                    \
            float d2 = d1 + 1024.0f;                                           \
            float e1f = __expf(two_tauinv * (float)c1 * __builtin_amdgcn_rcpf(d1)); \
            float e2f = __expf(two_tauinv * (float)c2 * __builtin_amdgcn_rcpf(d2)); \
            esum += e1f + e2f;                                                 \
            wtr  += __logf(tva[j]) * e1f + __logf(tvb[j]) * e2f;               \
            bool p1 = ((MAn) >> j) & 1u;                                       \
            bool p2 = ((MBn) >> j) & 1u;                                       \
            float q1 = p1 ? w1a[j] : 1.f - w1a[j];                             \
            float q2 = p1 ? w2a[j] : 1.f - w2a[j];                             \
            float q3 = p1 ? w3a[j] : 1.f - w3a[j];                             \
            float q4 = p2 ? w1b[j] : 1.f - w1b[j];                             \
            float q5 = p2 ? w2b[j] : 1.f - w2b[j];                             \
            float q6 = p2 ? w3b[j] : 1.f - w3b[j];                             \
            bce += __logf(((q1 * q2) * (q3 * q4)) * (q5 * q6));                \
        }                                                                      \
    } while (0)

    // ---- pipelined pairs: issue gp+1, compute gp (ping-pong reg sets) ----
    // stage 0: prefetch pair1, compute pair0
    v4f ntA = ntload(Tp + 256);  v4f ntB = ntload(Tp + 1280);
    v4f na1 = ntload(P1 + 256);  v4f nb1 = ntload(P1 + 1280);
    v4f na2 = ntload(P2 + 256);  v4f nb2 = ntload(P2 + 1280);
    v4f na3 = ntload(P3 + 256);  v4f nb3 = ntload(P3 + 1280);
    COMPUTE(mA0, mB0, cbA0, cbB0, 4 * lane, tA, tB, a1, b1, a2, b2, a3, b3);

    // stage 1: prefetch pair2 into set A, compute pair1
    tA = ntload(Tp + 512);  tB = ntload(Tp + 1536);
    a1 = ntload(P1 + 512);  b1 = ntload(P1 + 1536);
    a2 = ntload(P2 + 512);  b2 = ntload(P2 + 1536);
    a3 = ntload(P3 + 512);  b3 = ntload(P3 + 1536);
    COMPUTE(mA1, mB1, cbA1, cbB1, 256 + 4 * lane, ntA, ntB, na1, nb1, na2, nb2, na3, nb3);

    // stage 2: prefetch pair3 into set B, compute pair2
    ntA = ntload(Tp + 768);  ntB = ntload(Tp + 1792);
    na1 = ntload(P1 + 768);  nb1 = ntload(P1 + 1792);
    na2 = ntload(P2 + 768);  nb2 = ntload(P2 + 1792);
    na3 = ntload(P3 + 768);  nb3 = ntload(P3 + 1792);
    COMPUTE(mA2, mB2, cbA2, cbB2, 512 + 4 * lane, tA, tB, a1, b1, a2, b2, a3, b3);

    // stage 3: compute pair3
    COMPUTE(mA3, mB3, cbA3, cbB3, 768 + 4 * lane, ntA, ntB, na1, nb1, na2, nb2, na3, nb3);

#undef COMPUTE

    // ---- fold log(1/tau), wave-local reduces (no barrier until epilogue) ----
    wtr += LOG_TAU_INV * esum;
    #pragma unroll
    for (int o = 32; o > 0; o >>= 1) {
        esum += __shfl_down(esum, o, 64);
        wtr  += __shfl_down(wtr,  o, 64);
        bce  += __shfl_down(bce,  o, 64);
    }
    if (lane == 0) { srow[wv] = wtr / esum; sbce[wv] = bce; }
    __syncthreads();
    if (t == 0) {
        partials[blockIdx.x]        = srow[0] + srow[1] + srow[2] + srow[3];
        partials[NBLK + blockIdx.x] = sbce[0] + sbce[1] + sbce[2] + sbce[3];
    }
}

__global__ __launch_bounds__(TPB) void milecut_final_kernel(
    const float* __restrict__ partials, float* __restrict__ out)
{
    const int t = threadIdx.x;
    const float4* p4 = (const float4*)partials;   // 512 float4 total
    float4 a = p4[t];          // trunc region: f4 0..255
    float4 b = p4[256 + t];    // bce region:   f4 256..511
    float st = (a.x + a.y) + (a.z + a.w);
    float sb = (b.x + b.y) + (b.z + b.w);
    #pragma unroll
    for (int o = 32; o > 0; o >>= 1) {
        st += __shfl_down(st, o, 64);
        sb += __shfl_down(sb, o, 64);
    }
    __shared__ float s1[NW], s2[NW];
    const int lane = t & 63, wv = t >> 6;
    if (lane == 0) { s1[wv] = st; s2[wv] = sb; }
    __syncthreads();
    if (t == 0) {
        double St = 0.0, Sb = 0.0;
        #pragma unroll
        for (int w = 0; w < NW; ++w) { St += (double)s1[w]; Sb += (double)s2[w]; }
        double trunc_loss = -St / (double)B_DIM;                         // -sum(log*q)/B
        double vsum = -Sb / ((double)B_DIM * (double)L_DIM * (double)B_DIM);
        out[0] = (float)(0.5 * trunc_loss + 0.5 * vsum);
    }
}

extern "C" void kernel_launch(void* const* d_in, const int* in_sizes, int n_in,
                              void* d_out, int out_size, void* d_ws, size_t ws_size,
                              hipStream_t stream) {
    const float* trunc  = (const float*)d_in[0];
    const float* v1     = (const float*)d_in[1];
    const float* v2     = (const float*)d_in[2];
    const float* v3     = (const float*)d_in[3];
    const float* labels = (const float*)d_in[4];

    float* partials = (float*)d_ws;  // 2*NBLK*4 = 8 KB used

    milecut_row_kernel<<<NBLK, TPB, 0, stream>>>(trunc, v1, v2, v3, labels, partials);
    milecut_final_kernel<<<1, TPB, 0, stream>>>(partials, (float*)d_out);
}

// Round 2
// 162.091 us; speedup vs baseline: 1.0126x; 1.0126x over previous
//
#include <hip/hip_runtime.h>

#define B_DIM 4096
#define L_DIM 2048
#define TPB   256
#define NW    4
#define NBLK  B_DIM              // one block per ROW (R9)
#define TAU_INV 1.0526315789473684f
#define LOG_TAU_INV 0.05129329438755058f   // ln(1/0.95)

typedef float v4f __attribute__((ext_vector_type(4)));

// Nontemporal float4 load ('nt'): bypasses cache allocation — avoids the L3
// dirty-line service path left by the harness's input restore (R6: −13.5us).
__device__ __forceinline__ v4f ntload(const float* p) {
    return __builtin_nontemporal_load((const v4f*)p);
}

__device__ __forceinline__ unsigned nib(v4f y) {
    return (y.x > 0.5f ? 1u : 0u) | (y.y > 0.5f ? 2u : 0u)
         | (y.z > 0.5f ? 4u : 0u) | (y.w > 0.5f ? 8u : 0u);
}

// R9: one block per row, one wave per QUARTER-row (512 elems). Each wave's
// entire working set = 10 v4f loads (2 label + 8 data, 40 VGPRs), all issued
// up-front -> a single memory wait point per wave, hidden by 6 waves/SIMD of
// TLP (16384 waves total, 4x R8). One packed scan word per wave (6 shfls,
// was 24), ONE barrier per block to exchange the 4 wave label-count totals.
// Keeps R7's transcendental diet: one log of the 6-factor BCE product per
// element-pair (clamp at -100 provably inactive: p in (1e-4,1-1e-4)), and
// log(1/tau) folded out of the weighted trunc sum.
// Layout: wave wv owns elements [wv*512, wv*512+512); lane owns 4l..4l+3 of
// group g0 (offset 0) and g1 (offset +256). Packed scan: lo16=g0, hi16=g1
// (counts <= 256, fields exact).
__global__ __launch_bounds__(TPB) void milecut_row_kernel(
    const float* __restrict__ trunc,
    const float* __restrict__ view1,
    const float* __restrict__ view2,
    const float* __restrict__ view3,
    const float* __restrict__ labels,
    float* __restrict__ partials)
{
    const int t    = threadIdx.x;
    const int lane = t & 63;
    const int wv   = t >> 6;
    const int row  = blockIdx.x;

    __shared__ unsigned swtot[NW];     // packed per-wave label totals
    __shared__ float    sred[NW][3];   // esum, wtr, bce per wave

    const size_t base = (size_t)row * L_DIM + (size_t)(wv << 9) + 4 * lane;
    const float* Lp = labels + base;
    const float* Tp = trunc  + base;
    const float* P1 = view1  + base;
    const float* P2 = view2  + base;
    const float* P3 = view3  + base;

    // ---- issue ALL 10 loads up-front (single wait point) ----
    v4f y0  = ntload(Lp);        v4f y1  = ntload(Lp + 256);
    v4f t0  = ntload(Tp);        v4f t1  = ntload(Tp + 256);
    v4f w10 = ntload(P1);        v4f w11 = ntload(P1 + 256);
    v4f w20 = ntload(P2);        v4f w21 = ntload(P2 + 256);
    v4f w30 = ntload(P3);        v4f w31 = ntload(P3 + 256);

    // ---- masks + single packed wave scan (waits only on the label loads) ----
    unsigned m0 = nib(y0), m1 = nib(y1);
    unsigned pv = (unsigned)__popc(m0) | ((unsigned)__popc(m1) << 16);
    unsigned incl = pv;
    #pragma unroll
    for (int o = 1; o < 64; o <<= 1) {
        unsigned n = (unsigned)__shfl_up((int)incl, o, 64);
        if (lane >= o) incl += n;
    }
    if (lane == 63) swtot[wv] = incl;
    __syncthreads();

    // prefix over the 8 groups of the row (group order: wv*2, wv*2+1)
    unsigned prefix = 0, total = 0, ownA = swtot[wv] & 0xffffu;
    #pragma unroll
    for (int w = 0; w < NW; ++w) {
        unsigned x = swtot[w];
        unsigned s = (x & 0xffffu) + (x >> 16);
        if (w < wv) prefix += s;
        total += s;
    }
    unsigned eo  = incl - pv;                      // exclusive, packed
    unsigned cb0 = prefix + (eo & 0xffffu);        // cumulative base, group 0
    unsigned cb1 = prefix + ownA + (eo >> 16);     // cumulative base, group 1
    float ftotal = (float)total;

    // ---- fused elementwise over the 4 element-pairs ----
    float esum = 0.f, wtr = 0.f, bce = 0.f;
    const float two_tauinv = 2.0f * TAU_INV;
    float tva[4] = {t0.x,  t0.y,  t0.z,  t0.w};
    float tvb[4] = {t1.x,  t1.y,  t1.z,  t1.w};
    float q1a[4] = {w10.x, w10.y, w10.z, w10.w};
    float q1b[4] = {w11.x, w11.y, w11.z, w11.w};
    float q2a[4] = {w20.x, w20.y, w20.z, w20.w};
    float q2b[4] = {w21.x, w21.y, w21.z, w21.w};
    float q3a[4] = {w30.x, w30.y, w30.z, w30.w};
    float q3b[4] = {w31.x, w31.y, w31.z, w31.w};
    const float dbase = (float)((wv << 9) + 4 * lane + 1) + ftotal;
    #pragma unroll
    for (int j = 0; j < 4; ++j) {
        unsigned c1 = cb0 + (unsigned)__popc(m0 & ((2u << j) - 1u));
        unsigned c2 = cb1 + (unsigned)__popc(m1 & ((2u << j) - 1u));
        float d1 = dbase + (float)j;
        float d2 = d1 + 256.0f;
        float e1 = __expf(two_tauinv * (float)c1 * __builtin_amdgcn_rcpf(d1));
        float e2 = __expf(two_tauinv * (float)c2 * __builtin_amdgcn_rcpf(d2));
        esum += e1 + e2;
        wtr  += __logf(tva[j]) * e1 + __logf(tvb[j]) * e2;
        bool p1 = (m0 >> j) & 1u;
        bool p2 = (m1 >> j) & 1u;
        float f1 = p1 ? q1a[j] : 1.f - q1a[j];
        float f2 = p1 ? q2a[j] : 1.f - q2a[j];
        float f3 = p1 ? q3a[j] : 1.f - q3a[j];
        float f4 = p2 ? q1b[j] : 1.f - q1b[j];
        float f5 = p2 ? q2b[j] : 1.f - q2b[j];
        float f6 = p2 ? q3b[j] : 1.f - q3b[j];
        bce += __logf(((f1 * f2) * (f3 * f4)) * (f5 * f6));
    }
    wtr += LOG_TAU_INV * esum;   // fold the /tau in, once per wave

    // ---- wave-local reduce, then one cross-wave combine ----
    #pragma unroll
    for (int o = 32; o > 0; o >>= 1) {
        esum += __shfl_down(esum, o, 64);
        wtr  += __shfl_down(wtr,  o, 64);
        bce  += __shfl_down(bce,  o, 64);
    }
    if (lane == 0) { sred[wv][0] = esum; sred[wv][1] = wtr; sred[wv][2] = bce; }
    __syncthreads();
    if (t == 0) {
        float es = sred[0][0] + sred[1][0] + sred[2][0] + sred[3][0];
        float wt = sred[0][1] + sred[1][1] + sred[2][1] + sred[3][1];
        float bc = sred[0][2] + sred[1][2] + sred[2][2] + sred[3][2];
        partials[row]        = wt / es;     // this row's sum_j log(t/tau)*q_j
        partials[NBLK + row] = bc;          // raw combined bce sum
    }
}

__global__ __launch_bounds__(TPB) void milecut_final_kernel(
    const float* __restrict__ partials, float* __restrict__ out)
{
    const int t = threadIdx.x;
    const float4* p4 = (const float4*)partials;   // 2048 f4: 0..1023 trunc, 1024..2047 bce
    float st = 0.f, sb = 0.f;
    #pragma unroll
    for (int i = 0; i < 4; ++i) {
        float4 a = p4[t + 256 * i];
        float4 b = p4[1024 + t + 256 * i];
        st += (a.x + a.y) + (a.z + a.w);
        sb += (b.x + b.y) + (b.z + b.w);
    }
    #pragma unroll
    for (int o = 32; o > 0; o >>= 1) {
        st += __shfl_down(st, o, 64);
        sb += __shfl_down(sb, o, 64);
    }
    __shared__ float s1[NW], s2[NW];
    const int lane = t & 63, wv = t >> 6;
    if (lane == 0) { s1[wv] = st; s2[wv] = sb; }
    __syncthreads();
    if (t == 0) {
        double St = 0.0, Sb = 0.0;
        #pragma unroll
        for (int w = 0; w < NW; ++w) { St += (double)s1[w]; Sb += (double)s2[w]; }
        double trunc_loss = -St / (double)B_DIM;                         // -sum(log*q)/B
        double vsum = -Sb / ((double)B_DIM * (double)L_DIM * (double)B_DIM);
        out[0] = (float)(0.5 * trunc_loss + 0.5 * vsum);
    }
}

extern "C" void kernel_launch(void* const* d_in, const int* in_sizes, int n_in,
                              void* d_out, int out_size, void* d_ws, size_t ws_size,
                              hipStream_t stream) {
    const float* trunc  = (const float*)d_in[0];
    const float* v1     = (const float*)d_in[1];
    const float* v2     = (const float*)d_in[2];
    const float* v3     = (const float*)d_in[3];
    const float* labels = (const float*)d_in[4];

    float* partials = (float*)d_ws;  // 2*NBLK*4 = 32 KB used

    milecut_row_kernel<<<NBLK, TPB, 0, stream>>>(trunc, v1, v2, v3, labels, partials);
    milecut_final_kernel<<<1, TPB, 0, stream>>>(partials, (float*)d_out);
}